// Round 7
// baseline (809.893 us; speedup 1.0000x reference)
//
#include <hip/hip_runtime.h>
#include <stdint.h>

#define N_NODES_C 100000
#define N_EDGES_C 1600000
#define DIM 64
#define BN_EPS_C 1e-5f
#define BSH 7                      // 128 nodes per bucket
#define NB 782                     // ceil(100000 / 128)
#define CH 8192                    // edges per binscatter block
#define TSH 13                     // source tile = src >> 13 (8192 nodes, 1 MB of hs)
#define NT 13                      // tiles: 100000 >> 13 = 12 -> 0..12

// ---------- index helper: supports int32 or int64 edge_index ----------
__device__ __forceinline__ int ld_idx(const void* p, int is64, size_t i) {
    if (is64) return (int)((const long long*)p)[i];
    return ((const int*)p)[i];
}

__device__ __forceinline__ float bflo(unsigned int u) {
    return __uint_as_float(u << 16);
}
__device__ __forceinline__ float bfhi(unsigned int u) {
    return __uint_as_float(u & 0xFFFF0000u);
}
__device__ __forceinline__ unsigned short f2bf(float f) {   // round-to-nearest-even
    unsigned int u = __float_as_uint(f);
    return (unsigned short)((u + 0x7FFF + ((u >> 16) & 1)) >> 16);
}

// Probe: if edge_index is int64, the high 32-bit word of every element is 0
__global__ void probe_kernel(const unsigned int* __restrict__ p, int* __restrict__ flag) {
    if (threadIdx.x == 0 && blockIdx.x == 0) {
        int is64 = 1;
        for (int i = 1; i < 64; i += 2) {
            if (p[i] != 0u) { is64 = 0; break; }
        }
        *flag = is64;
    }
}

// ---------- bucket histogram of targets ----------
__global__ __launch_bounds__(256) void hist_kernel(const void* __restrict__ ei,
                                                   const int* __restrict__ flag,
                                                   int* __restrict__ bucket_cnt) {
    __shared__ int hist[NB];
    for (int i = threadIdx.x; i < NB; i += 256) hist[i] = 0;
    __syncthreads();
    int is64 = *flag;
    int stride = gridDim.x * blockDim.x;
    for (int e = blockIdx.x * blockDim.x + threadIdx.x; e < N_EDGES_C; e += stride) {
        int tg = ld_idx(ei, is64, (size_t)N_EDGES_C + e);
        atomicAdd(&hist[tg >> BSH], 1);
    }
    __syncthreads();
    for (int i = threadIdx.x; i < NB; i += 256) {
        int c = hist[i];
        if (c) atomicAdd(&bucket_cnt[i], c);
    }
}

// ---------- single-block prefix sum over buckets ----------
__global__ __launch_bounds__(1024) void bucketscan_kernel(const int* __restrict__ bucket_cnt,
                                                          int* __restrict__ bucket_base,
                                                          int* __restrict__ bucket_cursor) {
    __shared__ int s[1024];
    int t = threadIdx.x;
    int v = (t < NB) ? bucket_cnt[t] : 0;
    s[t] = v;
    __syncthreads();
    for (int off = 1; off < 1024; off <<= 1) {
        int u = (t >= off) ? s[t - off] : 0;
        __syncthreads();
        s[t] += u;
        __syncthreads();
    }
    if (t < NB) {
        int excl = s[t] - v;
        bucket_base[t] = excl;
        bucket_cursor[t] = excl;
    }
}

// ---------- binned scatter: pack (tgt_local<<17 | src), locally grouped writes ----------
__global__ __launch_bounds__(256) void binscatter_kernel(const void* __restrict__ ei,
                                                         const int* __restrict__ flag,
                                                         int* __restrict__ bucket_cursor,
                                                         unsigned int* __restrict__ csr) {
    __shared__ int hist[NB];
    __shared__ int base[NB];
    int is64 = *flag;
    int e0 = blockIdx.x * CH;
    int eend = min(e0 + CH, N_EDGES_C);
    for (int i = threadIdx.x; i < NB; i += 256) hist[i] = 0;
    __syncthreads();
    for (int e = e0 + threadIdx.x; e < eend; e += 256) {
        int tg = ld_idx(ei, is64, (size_t)N_EDGES_C + e);
        atomicAdd(&hist[tg >> BSH], 1);
    }
    __syncthreads();
    for (int i = threadIdx.x; i < NB; i += 256) {
        int c = hist[i];
        base[i] = c ? atomicAdd(&bucket_cursor[i], c) : 0;
        hist[i] = 0;
    }
    __syncthreads();
    for (int e = e0 + threadIdx.x; e < eend; e += 256) {
        int s  = ld_idx(ei, is64, (size_t)e);
        int tg = ld_idx(ei, is64, (size_t)N_EDGES_C + e);
        int b  = tg >> BSH;
        int tl = tg & 127;
        int pos = base[b] + atomicAdd(&hist[b], 1);
        csr[pos] = ((unsigned int)tl << 17) | (unsigned int)s;
    }
}

// ---------- per-bucket counting sort by src tile -> csr3 (keeps tl<<17|src);
// ---------- emits tb[bk*(NT+1)+k] and per-node dinv ----------
__global__ __launch_bounds__(256) void sort2_kernel(const unsigned int* __restrict__ csr,
                                                    const int* __restrict__ bucket_base,
                                                    const int* __restrict__ bucket_cnt,
                                                    unsigned int* __restrict__ csr3,
                                                    int* __restrict__ tb,
                                                    float* __restrict__ dinv) {
    __shared__ int cntT[NT];
    __shared__ int baseT[NT + 1];
    __shared__ int curT[NT];
    __shared__ int cnt128[128];
    int bk = blockIdx.x;
    int t = threadIdx.x;
    if (t < NT) cntT[t] = 0;
    if (t < 128) cnt128[t] = 0;
    __syncthreads();
    int base = bucket_base[bk], n = bucket_cnt[bk];
    for (int i = t; i < n; i += 256) {
        unsigned int v = csr[base + i];
        atomicAdd(&cntT[(v & 0x1FFFF) >> TSH], 1);
        atomicAdd(&cnt128[v >> 17], 1);
    }
    __syncthreads();
    if (t == 0) {
        int run = 0;
        for (int k = 0; k < NT; ++k) { baseT[k] = run; run += cntT[k]; }
        baseT[NT] = run;
    }
    __syncthreads();
    if (t < NT) curT[t] = base + baseT[t];
    if (t <= NT) tb[bk * (NT + 1) + t] = base + baseT[t];
    if (t < 128) {
        int node = (bk << BSH) + t;
        if (node < N_NODES_C) dinv[node] = rsqrtf((float)(cnt128[t] + 1));
    }
    __syncthreads();
    for (int i = t; i < n; i += 256) {
        unsigned int v = csr[base + i];
        int key = (int)((v & 0x1FFFF) >> TSH);
        int pos = atomicAdd(&curT[key], 1);
        csr3[pos] = v;
    }
}

// ---------- hs = (x @ W^T) * dinv[row]  -> bf16 ----------
__global__ __launch_bounds__(256) void gemm_kernel(const float* __restrict__ x,
                                                   const float* __restrict__ W,
                                                   const float* __restrict__ dinv,
                                                   unsigned short* __restrict__ hs) {
    __shared__ float Wl[DIM * 65];
    __shared__ float xs[32][DIM];
    int t = threadIdx.x;
    for (int i = t; i < DIM * DIM; i += 256) {
        Wl[(i >> 6) * 65 + (i & 63)] = W[i];
    }
    int r0 = blockIdx.x * 32;
    for (int i = t; i < 32 * DIM; i += 256) {
        int row = i >> 6, col = i & 63;
        int r = r0 + row;
        xs[row][col] = (r < N_NODES_C) ? x[(size_t)r * DIM + col] : 0.0f;
    }
    __syncthreads();
    int wv = t >> 6, c = t & 63;
    for (int it = 0; it < 8; ++it) {
        int rl = it * 4 + wv;
        int r = r0 + rl;
        float acc = 0.0f;
#pragma unroll
        for (int k = 0; k < DIM; ++k) acc += xs[rl][k] * Wl[c * 65 + k];
        if (r < N_NODES_C) hs[(size_t)r * DIM + c] = f2bf(acc * dinv[r]);
    }
}

// ---------- bucket aggregate: LDS accum, tile-phased edges, 8-deep unroll.
// out[t] = (sum_src hs[src] + hs[t]) * dinv[t] + b ; fused BN stats ----------
__global__ __launch_bounds__(256) void agg2_kernel(const unsigned int* __restrict__ csr3,
                                                   const int* __restrict__ tb,
                                                   const float* __restrict__ dinv,
                                                   const unsigned int* __restrict__ hs2,
                                                   const unsigned short* __restrict__ hs16,
                                                   const float* __restrict__ b_,
                                                   float* __restrict__ out,
                                                   float* __restrict__ sums,
                                                   float* __restrict__ sumsq) {
    __shared__ float accum[128 * DIM];   // 32 KB
    int bk = blockIdx.x;
    int t = threadIdx.x;
    int hw = t >> 5;        // half-wave 0..7
    int c2 = t & 31;        // channel pair
    for (int i = t; i < 128 * DIM; i += 256) accum[i] = 0.0f;
    __syncthreads();

    for (int tt = 0; tt < NT; ++tt) {
        int s0 = tb[bk * (NT + 1) + tt];
        int s1 = tb[bk * (NT + 1) + tt + 1];
        for (int j = s0 + hw * 8; j < s1; j += 64) {
            int m = s1 - j;              // >= 1
            unsigned int ev[8], u[8];
#pragma unroll
            for (int k = 0; k < 8; ++k) {
                int idx = (k < m) ? k : (m - 1);
                ev[k] = csr3[j + idx];
            }
#pragma unroll
            for (int k = 0; k < 8; ++k) {
                u[k] = hs2[(size_t)(ev[k] & 0x1FFFF) * 32 + c2];
            }
#pragma unroll
            for (int k = 0; k < 8; ++k) {
                if (k < m) {
                    int tl = (int)(ev[k] >> 17);
                    atomicAdd(&accum[tl * DIM + 2 * c2],     bflo(u[k]));
                    atomicAdd(&accum[tl * DIM + 2 * c2 + 1], bfhi(u[k]));
                }
            }
        }
    }
    __syncthreads();

    // epilogue: 4 waves cover 128 rows; lane = channel
    int lane = t & 63, wv = t >> 6;
    float bc = b_[lane];
    float ls = 0.0f, lq = 0.0f;
    for (int r = wv; r < 128; r += 4) {
        int node = (bk << BSH) + r;
        if (node >= N_NODES_C) break;
        float hself = bflo((unsigned int)hs16[(size_t)node * DIM + lane]);
        float dt = dinv[node];
        float v = fmaf(accum[r * DIM + lane] + hself, dt, bc);
        out[(size_t)node * DIM + lane] = v;
        ls += v;
        lq += v * v;
    }
    __shared__ float ssum[256], ssq[256];
    ssum[t] = ls;
    ssq[t] = lq;
    __syncthreads();
    if (t < 64) {
        float a = ssum[lane] + ssum[64 + lane] + ssum[128 + lane] + ssum[192 + lane];
        float q = ssq[lane] + ssq[64 + lane] + ssq[128 + lane] + ssq[192 + lane];
        unsafeAtomicAdd(&sums[lane], a);
        unsafeAtomicAdd(&sumsq[lane], q);
    }
}

__global__ void bnparam_kernel(const float* __restrict__ sums,
                               const float* __restrict__ sumsq,
                               const float* __restrict__ gamma,
                               const float* __restrict__ beta,
                               float* __restrict__ scale,
                               float* __restrict__ shift) {
    int c = threadIdx.x;
    if (c < DIM) {
        float m = sums[c] * (1.0f / N_NODES_C);
        float var = sumsq[c] * (1.0f / N_NODES_C) - m * m;
        float sc = gamma[c] * rsqrtf(var + BN_EPS_C);
        scale[c] = sc;
        shift[c] = beta[c] - m * sc;
    }
}

__global__ __launch_bounds__(256) void bnrelu_kernel(float4* __restrict__ out,
                                                     const float* __restrict__ scale,
                                                     const float* __restrict__ shift) {
    const int n4 = N_NODES_C * (DIM / 4);
    int stride = gridDim.x * blockDim.x;
    for (int i = blockIdx.x * blockDim.x + threadIdx.x; i < n4; i += stride) {
        int cb = (i & 15) * 4;
        float4 v = out[i];
        v.x = fmaxf(fmaf(v.x, scale[cb + 0], shift[cb + 0]), 0.0f);
        v.y = fmaxf(fmaf(v.y, scale[cb + 1], shift[cb + 1]), 0.0f);
        v.z = fmaxf(fmaf(v.z, scale[cb + 2], shift[cb + 2]), 0.0f);
        v.w = fmaxf(fmaf(v.w, scale[cb + 3], shift[cb + 3]), 0.0f);
        out[i] = v;
    }
}

extern "C" void kernel_launch(void* const* d_in, const int* in_sizes, int n_in,
                              void* d_out, int out_size, void* d_ws, size_t ws_size,
                              hipStream_t stream) {
    const float* x     = (const float*)d_in[0];
    const void*  ei    = d_in[1];
    const float* W     = (const float*)d_in[2];
    const float* b     = (const float*)d_in[3];
    const float* gamma = (const float*)d_in[4];
    const float* beta  = (const float*)d_in[5];
    float* out = (float*)d_out;

    char* ws = (char*)d_ws;
    int*   flag          = (int*)(ws + 0);
    int*   bucket_cnt    = (int*)(ws + 256);       // 3328 B
    int*   bucket_base   = (int*)(ws + 3584);      // 3328 B
    int*   bucket_cursor = (int*)(ws + 6912);      // 3328 B
    float* dinv          = (float*)(ws + 10240);   // 400000 B
    int*   tb            = (int*)(ws + 410240);    // 782*14*4 = 43792 B
    float* sums          = (float*)(ws + 454144);  // 256 B
    float* sumsq         = (float*)(ws + 454400);  // 256 B
    float* scale         = (float*)(ws + 454656);  // 256 B
    float* shift         = (float*)(ws + 454912);  // 256 B
    unsigned int* csr3   = (unsigned int*)(ws + 455168);   // 6,400,000 B
    unsigned int* csr    = (unsigned int*)(ws + 6855168);  // 6,400,000 B (dead after sort2)
    unsigned short* hs   = (unsigned short*)(ws + 6855168); // 12,800,000 B (overlays csr)

    hipMemsetAsync(bucket_cnt, 0, NB * sizeof(int), stream);
    hipMemsetAsync(sums, 0, 512, stream);  // sums + sumsq contiguous

    probe_kernel<<<1, 64, 0, stream>>>((const unsigned int*)ei, flag);
    hist_kernel<<<256, 256, 0, stream>>>(ei, flag, bucket_cnt);
    bucketscan_kernel<<<1, 1024, 0, stream>>>(bucket_cnt, bucket_base, bucket_cursor);
    binscatter_kernel<<<(N_EDGES_C + CH - 1) / CH, 256, 0, stream>>>(ei, flag,
                                                                    bucket_cursor, csr);
    sort2_kernel<<<NB, 256, 0, stream>>>(csr, bucket_base, bucket_cnt, csr3, tb, dinv);
    gemm_kernel<<<(N_NODES_C + 31) / 32, 256, 0, stream>>>(x, W, dinv, hs);
    agg2_kernel<<<NB, 256, 0, stream>>>(csr3, tb, dinv,
                                        (const unsigned int*)hs,
                                        (const unsigned short*)hs, b,
                                        out, sums, sumsq);
    bnparam_kernel<<<1, 64, 0, stream>>>(sums, sumsq, gamma, beta, scale, shift);
    bnrelu_kernel<<<1024, 256, 0, stream>>>((float4*)out, scale, shift);
}

// Round 8
// 251.548 us; speedup vs baseline: 3.2196x; 3.2196x over previous
//
#include <hip/hip_runtime.h>
#include <stdint.h>

#define N_NODES_C 100000
#define N_EDGES_C 1600000
#define DIM 64
#define BN_EPS_C 1e-5f
#define BSH 7                      // 128 nodes per bucket
#define NB 782                     // ceil(100000 / 128)
#define CH 8192                    // edges per binscatter block

// ---------- index helper: supports int32 or int64 edge_index ----------
__device__ __forceinline__ int ld_idx(const void* p, int is64, size_t i) {
    if (is64) return (int)((const long long*)p)[i];
    return ((const int*)p)[i];
}

// Inline probe: if edge_index is int64, the high word of every element is 0.
// Values are in [0,100000); for int32 inputs 32 consecutive odd words being
// all zero is impossible for random data. Wave-uniform result.
__device__ __forceinline__ int probe_is64(const unsigned int* __restrict__ p) {
    int lane = threadIdx.x & 63;
    unsigned int v = (lane < 32) ? p[2 * lane + 1] : 0u;
    return __ballot(v != 0u) == 0ull;
}

__device__ __forceinline__ float bflo(unsigned int u) {
    return __uint_as_float(u << 16);
}
__device__ __forceinline__ float bfhi(unsigned int u) {
    return __uint_as_float(u & 0xFFFF0000u);
}
__device__ __forceinline__ unsigned short f2bf(float f) {   // round-to-nearest-even
    unsigned int u = __float_as_uint(f);
    return (unsigned short)((u + 0x7FFF + ((u >> 16) & 1)) >> 16);
}

// ---------- bucket histogram of targets ----------
__global__ __launch_bounds__(256) void hist_kernel(const void* __restrict__ ei,
                                                   int* __restrict__ bucket_cnt) {
    __shared__ int hist[NB];
    for (int i = threadIdx.x; i < NB; i += 256) hist[i] = 0;
    __syncthreads();
    int is64 = probe_is64((const unsigned int*)ei);
    int stride = gridDim.x * blockDim.x;
    for (int e = blockIdx.x * blockDim.x + threadIdx.x; e < N_EDGES_C; e += stride) {
        int tg = ld_idx(ei, is64, (size_t)N_EDGES_C + e);
        atomicAdd(&hist[tg >> BSH], 1);
    }
    __syncthreads();
    for (int i = threadIdx.x; i < NB; i += 256) {
        int c = hist[i];
        if (c) atomicAdd(&bucket_cnt[i], c);
    }
}

// ---------- single-block prefix sum over buckets ----------
__global__ __launch_bounds__(1024) void bucketscan_kernel(const int* __restrict__ bucket_cnt,
                                                          int* __restrict__ bucket_base,
                                                          int* __restrict__ bucket_cursor) {
    __shared__ int s[1024];
    int t = threadIdx.x;
    int v = (t < NB) ? bucket_cnt[t] : 0;
    s[t] = v;
    __syncthreads();
    for (int off = 1; off < 1024; off <<= 1) {
        int u = (t >= off) ? s[t - off] : 0;
        __syncthreads();
        s[t] += u;
        __syncthreads();
    }
    if (t < NB) {
        int excl = s[t] - v;
        bucket_base[t] = excl;
        bucket_cursor[t] = excl;
    }
}

// ---------- binned scatter: pack (tgt_local<<17 | src), locally grouped writes ----------
__global__ __launch_bounds__(256) void binscatter_kernel(const void* __restrict__ ei,
                                                         int* __restrict__ bucket_cursor,
                                                         unsigned int* __restrict__ csr) {
    __shared__ int hist[NB];
    __shared__ int base[NB];
    int is64 = probe_is64((const unsigned int*)ei);
    int e0 = blockIdx.x * CH;
    int eend = min(e0 + CH, N_EDGES_C);
    for (int i = threadIdx.x; i < NB; i += 256) hist[i] = 0;
    __syncthreads();
    for (int e = e0 + threadIdx.x; e < eend; e += 256) {
        int tg = ld_idx(ei, is64, (size_t)N_EDGES_C + e);
        atomicAdd(&hist[tg >> BSH], 1);
    }
    __syncthreads();
    for (int i = threadIdx.x; i < NB; i += 256) {
        int c = hist[i];
        base[i] = c ? atomicAdd(&bucket_cursor[i], c) : 0;
        hist[i] = 0;
    }
    __syncthreads();
    for (int e = e0 + threadIdx.x; e < eend; e += 256) {
        int s  = ld_idx(ei, is64, (size_t)e);
        int tg = ld_idx(ei, is64, (size_t)N_EDGES_C + e);
        int b  = tg >> BSH;
        int tl = tg & 127;
        int pos = base[b] + atomicAdd(&hist[b], 1);
        csr[pos] = ((unsigned int)tl << 17) | (unsigned int)s;
    }
}

// ---------- per-bucket node-sort: csr -> csr2 (src only, sorted by target node);
// ---------- also emits rowbase[N+1], dinv ----------
__global__ __launch_bounds__(256) void sort_kernel(const unsigned int* __restrict__ csr,
                                                   const int* __restrict__ bucket_base,
                                                   const int* __restrict__ bucket_cnt,
                                                   int* __restrict__ csr2,
                                                   int* __restrict__ rowbase,
                                                   float* __restrict__ dinv) {
    __shared__ int cnt[128];
    __shared__ int sbase[129];
    __shared__ int cur[128];
    int bk = blockIdx.x;
    int t = threadIdx.x;
    if (t < 128) cnt[t] = 0;
    __syncthreads();
    int base = bucket_base[bk], n = bucket_cnt[bk];
    for (int i = t; i < n; i += 256) {
        atomicAdd(&cnt[csr[base + i] >> 17], 1);
    }
    __syncthreads();
    if (t == 0) {
        int run = 0;
        for (int k = 0; k < 128; ++k) { sbase[k] = run; run += cnt[k]; }
        sbase[128] = run;
    }
    __syncthreads();
    if (t < 128) {
        cur[t] = base + sbase[t];
        int node = (bk << BSH) + t;
        if (node < N_NODES_C) {
            rowbase[node] = base + sbase[t];
            dinv[node] = rsqrtf((float)(cnt[t] + 1));   // +1 self-loop
        }
    }
    if (bk == 0 && t == 0) rowbase[N_NODES_C] = N_EDGES_C;
    __syncthreads();
    for (int i = t; i < n; i += 256) {
        unsigned int v = csr[base + i];
        int tl = v >> 17;
        int pos = atomicAdd(&cur[tl], 1);
        csr2[pos] = (int)(v & 0x1FFFF);
    }
}

// ---------- hs = (x @ W^T) * dinv[row]  -> bf16 ----------
__global__ __launch_bounds__(256) void gemm_kernel(const float* __restrict__ x,
                                                   const float* __restrict__ W,
                                                   const float* __restrict__ dinv,
                                                   unsigned short* __restrict__ hs) {
    __shared__ float Wl[DIM * 65];
    __shared__ float xs[32][DIM];
    int t = threadIdx.x;
    for (int i = t; i < DIM * DIM; i += 256) {
        Wl[(i >> 6) * 65 + (i & 63)] = W[i];
    }
    int r0 = blockIdx.x * 32;
    for (int i = t; i < 32 * DIM; i += 256) {
        int row = i >> 6, col = i & 63;
        int r = r0 + row;
        xs[row][col] = (r < N_NODES_C) ? x[(size_t)r * DIM + col] : 0.0f;
    }
    __syncthreads();
    int wv = t >> 6, c = t & 63;
    for (int it = 0; it < 8; ++it) {
        int rl = it * 4 + wv;
        int r = r0 + rl;
        float acc = 0.0f;
#pragma unroll
        for (int k = 0; k < DIM; ++k) acc += xs[rl][k] * Wl[c * 65 + k];
        if (r < N_NODES_C) hs[(size_t)r * DIM + c] = f2bf(acc * dinv[r]);
    }
}

// ---------- gather: two nodes per wave (half-wave per node, lane = channel pair),
// 2-deep software pipeline: issue batch k+1's idx+hs loads before consuming batch k.
// out[t] = (sum_src hs[src] + hs[t]) * dinv[t] + b ; fused BN stats ----------
__global__ __launch_bounds__(256) void gather_kernel(const int* __restrict__ csr2,
                                                     const int* __restrict__ rowbase,
                                                     const float* __restrict__ dinv,
                                                     const unsigned int* __restrict__ hs2,
                                                     const float* __restrict__ b_,
                                                     float2* __restrict__ out,
                                                     float* __restrict__ sums,
                                                     float* __restrict__ sumsq) {
    int lane = threadIdx.x & 63;
    int half = lane >> 5;
    int c2 = lane & 31;
    int wid = blockIdx.x * (blockDim.x >> 6) + (threadIdx.x >> 6);
    int nw = gridDim.x * (blockDim.x >> 6);
    float2 bb = ((const float2*)b_)[c2];
    float s0a = 0.0f, q0a = 0.0f, s1a = 0.0f, q1a = 0.0f;
    for (int p = wid; p < N_NODES_C / 2; p += nw) {
        int t = 2 * p + half;
        int base = rowbase[t];
        int end = rowbase[t + 1];
        float dt = dinv[t];
        float a0 = 0.0f, a1 = 0.0f;
        int j = base;
        int jend = base + ((end - base) & ~7);
        if (j < jend) {
            unsigned int ucur[8];
            {   // prologue: issue batch 0
                int idx[8];
#pragma unroll
                for (int k = 0; k < 8; ++k) idx[k] = csr2[j + k];
#pragma unroll
                for (int k = 0; k < 8; ++k) ucur[k] = hs2[(size_t)idx[k] * 32 + c2];
                j += 8;
            }
            while (j < jend) {
                int idx[8];
                unsigned int unxt[8];
#pragma unroll
                for (int k = 0; k < 8; ++k) idx[k] = csr2[j + k];
#pragma unroll
                for (int k = 0; k < 8; ++k) unxt[k] = hs2[(size_t)idx[k] * 32 + c2];
#pragma unroll
                for (int k = 0; k < 8; ++k) { a0 += bflo(ucur[k]); a1 += bfhi(ucur[k]); }
#pragma unroll
                for (int k = 0; k < 8; ++k) ucur[k] = unxt[k];
                j += 8;
            }
#pragma unroll
            for (int k = 0; k < 8; ++k) { a0 += bflo(ucur[k]); a1 += bfhi(ucur[k]); }
        }
        for (; j + 2 <= end; j += 2) {
            int sA = csr2[j + 0];
            int sB = csr2[j + 1];
            unsigned int uA = hs2[(size_t)sA * 32 + c2];
            unsigned int uB = hs2[(size_t)sB * 32 + c2];
            a0 += bflo(uA); a1 += bfhi(uA);
            a0 += bflo(uB); a1 += bfhi(uB);
        }
        if (j < end) {
            int s = csr2[j];
            unsigned int u = hs2[(size_t)s * 32 + c2];
            a0 += bflo(u); a1 += bfhi(u);
        }
        unsigned int ut = hs2[(size_t)t * 32 + c2];
        a0 = fmaf(a0 + bflo(ut), dt, bb.x);
        a1 = fmaf(a1 + bfhi(ut), dt, bb.y);
        out[(size_t)t * 32 + c2] = make_float2(a0, a1);
        s0a += a0; q0a += a0 * a0;
        s1a += a1; q1a += a1 * a1;
    }
    __shared__ float r0[256], r1[256], r2[256], r3[256];
    r0[threadIdx.x] = s0a; r1[threadIdx.x] = q0a;
    r2[threadIdx.x] = s1a; r3[threadIdx.x] = q1a;
    __syncthreads();
    if (threadIdx.x < 32) {
        float S0 = 0, Q0 = 0, S1 = 0, Q1 = 0;
        for (int k = threadIdx.x; k < 256; k += 32) {
            S0 += r0[k]; Q0 += r1[k]; S1 += r2[k]; Q1 += r3[k];
        }
        unsafeAtomicAdd(&sums[2 * threadIdx.x], S0);
        unsafeAtomicAdd(&sums[2 * threadIdx.x + 1], S1);
        unsafeAtomicAdd(&sumsq[2 * threadIdx.x], Q0);
        unsafeAtomicAdd(&sumsq[2 * threadIdx.x + 1], Q1);
    }
}

// ---------- BN params derived in-block + apply + ReLU ----------
__global__ __launch_bounds__(256) void bnrelu_kernel(float4* __restrict__ out,
                                                     const float* __restrict__ sums,
                                                     const float* __restrict__ sumsq,
                                                     const float* __restrict__ gamma,
                                                     const float* __restrict__ beta) {
    __shared__ float sc[DIM], sh[DIM];
    int t = threadIdx.x;
    if (t < DIM) {
        float m = sums[t] * (1.0f / N_NODES_C);
        float var = sumsq[t] * (1.0f / N_NODES_C) - m * m;
        float s = gamma[t] * rsqrtf(var + BN_EPS_C);
        sc[t] = s;
        sh[t] = beta[t] - m * s;
    }
    __syncthreads();
    const int n4 = N_NODES_C * (DIM / 4);
    int stride = gridDim.x * blockDim.x;
    for (int i = blockIdx.x * blockDim.x + t; i < n4; i += stride) {
        int cb = (i & 15) * 4;
        float4 v = out[i];
        v.x = fmaxf(fmaf(v.x, sc[cb + 0], sh[cb + 0]), 0.0f);
        v.y = fmaxf(fmaf(v.y, sc[cb + 1], sh[cb + 1]), 0.0f);
        v.z = fmaxf(fmaf(v.z, sc[cb + 2], sh[cb + 2]), 0.0f);
        v.w = fmaxf(fmaf(v.w, sc[cb + 3], sh[cb + 3]), 0.0f);
        out[i] = v;
    }
}

extern "C" void kernel_launch(void* const* d_in, const int* in_sizes, int n_in,
                              void* d_out, int out_size, void* d_ws, size_t ws_size,
                              hipStream_t stream) {
    const float* x     = (const float*)d_in[0];
    const void*  ei    = d_in[1];
    const float* W     = (const float*)d_in[2];
    const float* b     = (const float*)d_in[3];
    const float* gamma = (const float*)d_in[4];
    const float* beta  = (const float*)d_in[5];
    float* out = (float*)d_out;

    char* ws = (char*)d_ws;
    int*   bucket_cnt    = (int*)(ws + 256);      // 3328 B
    int*   bucket_base   = (int*)(ws + 3584);     // 3328 B
    int*   bucket_cursor = (int*)(ws + 6912);     // 3328 B
    float* dinv          = (float*)(ws + 10240);  // 400000 B
    int*   rowbase       = (int*)(ws + 410240);   // 400004 B (+pad)
    float* sums          = (float*)(ws + 810496); // 256 B
    float* sumsq         = (float*)(ws + 810752); // 256 B
    unsigned int* csr    = (unsigned int*)(ws + 811520);   // 6,400,000 B
    int*   csr2          = (int*)(ws + 7211520);           // 6,400,000 B
    unsigned short* hs   = (unsigned short*)(ws + 13611520); // 12,800,000 B

    hipMemsetAsync(bucket_cnt, 0, NB * sizeof(int), stream);
    hipMemsetAsync(sums, 0, 512, stream);  // sums + sumsq contiguous

    hist_kernel<<<256, 256, 0, stream>>>(ei, bucket_cnt);
    bucketscan_kernel<<<1, 1024, 0, stream>>>(bucket_cnt, bucket_base, bucket_cursor);
    binscatter_kernel<<<(N_EDGES_C + CH - 1) / CH, 256, 0, stream>>>(ei, bucket_cursor, csr);
    sort_kernel<<<NB, 256, 0, stream>>>(csr, bucket_base, bucket_cnt, csr2,
                                        rowbase, dinv);
    gemm_kernel<<<(N_NODES_C + 31) / 32, 256, 0, stream>>>(x, W, dinv, hs);
    gather_kernel<<<2048, 256, 0, stream>>>(csr2, rowbase, dinv,
                                            (const unsigned int*)hs, b,
                                            (float2*)out, sums, sumsq);
    bnrelu_kernel<<<1024, 256, 0, stream>>>((float4*)out, sums, sumsq, gamma, beta);
}

// Round 9
// 246.348 us; speedup vs baseline: 3.2876x; 1.0211x over previous
//
#include <hip/hip_runtime.h>
#include <stdint.h>

#define N_NODES_C 100000
#define N_EDGES_C 1600000
#define DIM 64
#define BN_EPS_C 1e-5f
#define BSH 7                      // 128 nodes per bucket
#define NB 782                     // ceil(100000 / 128)
#define CH 8192                    // edges per binscatter block

// ---------- index helper: supports int32 or int64 edge_index ----------
__device__ __forceinline__ int ld_idx(const void* p, int is64, size_t i) {
    if (is64) return (int)((const long long*)p)[i];
    return ((const int*)p)[i];
}

// Inline probe: if edge_index is int64, the high word of every element is 0.
__device__ __forceinline__ int probe_is64(const unsigned int* __restrict__ p) {
    int lane = threadIdx.x & 63;
    unsigned int v = (lane < 32) ? p[2 * lane + 1] : 0u;
    return __ballot(v != 0u) == 0ull;
}

__device__ __forceinline__ float bflo(unsigned int u) {
    return __uint_as_float(u << 16);
}
__device__ __forceinline__ float bfhi(unsigned int u) {
    return __uint_as_float(u & 0xFFFF0000u);
}
__device__ __forceinline__ unsigned short f2bf(float f) {   // round-to-nearest-even
    unsigned int u = __float_as_uint(f);
    return (unsigned short)((u + 0x7FFF + ((u >> 16) & 1)) >> 16);
}

// ---------- bucket histogram of targets ----------
__global__ __launch_bounds__(256) void hist_kernel(const void* __restrict__ ei,
                                                   int* __restrict__ bucket_cnt) {
    __shared__ int hist[NB];
    for (int i = threadIdx.x; i < NB; i += 256) hist[i] = 0;
    __syncthreads();
    int is64 = probe_is64((const unsigned int*)ei);
    int stride = gridDim.x * blockDim.x;
    for (int e = blockIdx.x * blockDim.x + threadIdx.x; e < N_EDGES_C; e += stride) {
        int tg = ld_idx(ei, is64, (size_t)N_EDGES_C + e);
        atomicAdd(&hist[tg >> BSH], 1);
    }
    __syncthreads();
    for (int i = threadIdx.x; i < NB; i += 256) {
        int c = hist[i];
        if (c) atomicAdd(&bucket_cnt[i], c);
    }
}

// ---------- single-block prefix sum over buckets ----------
__global__ __launch_bounds__(1024) void bucketscan_kernel(const int* __restrict__ bucket_cnt,
                                                          int* __restrict__ bucket_base,
                                                          int* __restrict__ bucket_cursor) {
    __shared__ int s[1024];
    int t = threadIdx.x;
    int v = (t < NB) ? bucket_cnt[t] : 0;
    s[t] = v;
    __syncthreads();
    for (int off = 1; off < 1024; off <<= 1) {
        int u = (t >= off) ? s[t - off] : 0;
        __syncthreads();
        s[t] += u;
        __syncthreads();
    }
    if (t < NB) {
        int excl = s[t] - v;
        bucket_base[t] = excl;
        bucket_cursor[t] = excl;
    }
}

// ---------- binned scatter: pack (tgt_local<<17 | src), locally grouped writes ----------
__global__ __launch_bounds__(256) void binscatter_kernel(const void* __restrict__ ei,
                                                         int* __restrict__ bucket_cursor,
                                                         unsigned int* __restrict__ csr) {
    __shared__ int hist[NB];
    __shared__ int base[NB];
    int is64 = probe_is64((const unsigned int*)ei);
    int e0 = blockIdx.x * CH;
    int eend = min(e0 + CH, N_EDGES_C);
    for (int i = threadIdx.x; i < NB; i += 256) hist[i] = 0;
    __syncthreads();
    for (int e = e0 + threadIdx.x; e < eend; e += 256) {
        int tg = ld_idx(ei, is64, (size_t)N_EDGES_C + e);
        atomicAdd(&hist[tg >> BSH], 1);
    }
    __syncthreads();
    for (int i = threadIdx.x; i < NB; i += 256) {
        int c = hist[i];
        base[i] = c ? atomicAdd(&bucket_cursor[i], c) : 0;
        hist[i] = 0;
    }
    __syncthreads();
    for (int e = e0 + threadIdx.x; e < eend; e += 256) {
        int s  = ld_idx(ei, is64, (size_t)e);
        int tg = ld_idx(ei, is64, (size_t)N_EDGES_C + e);
        int b  = tg >> BSH;
        int tl = tg & 127;
        int pos = base[b] + atomicAdd(&hist[b], 1);
        csr[pos] = ((unsigned int)tl << 17) | (unsigned int)s;
    }
}

// ---------- per-bucket node-sort: csr -> csr2 (src only, sorted by target node);
// ---------- also emits rowbase[N+1], dinv ----------
__global__ __launch_bounds__(256) void sort_kernel(const unsigned int* __restrict__ csr,
                                                   const int* __restrict__ bucket_base,
                                                   const int* __restrict__ bucket_cnt,
                                                   int* __restrict__ csr2,
                                                   int* __restrict__ rowbase,
                                                   float* __restrict__ dinv) {
    __shared__ int cnt[128];
    __shared__ int sbase[129];
    __shared__ int cur[128];
    int bk = blockIdx.x;
    int t = threadIdx.x;
    if (t < 128) cnt[t] = 0;
    __syncthreads();
    int base = bucket_base[bk], n = bucket_cnt[bk];
    for (int i = t; i < n; i += 256) {
        atomicAdd(&cnt[csr[base + i] >> 17], 1);
    }
    __syncthreads();
    if (t == 0) {
        int run = 0;
        for (int k = 0; k < 128; ++k) { sbase[k] = run; run += cnt[k]; }
        sbase[128] = run;
    }
    __syncthreads();
    if (t < 128) {
        cur[t] = base + sbase[t];
        int node = (bk << BSH) + t;
        if (node < N_NODES_C) {
            rowbase[node] = base + sbase[t];
            dinv[node] = rsqrtf((float)(cnt[t] + 1));   // +1 self-loop
        }
    }
    if (bk == 0 && t == 0) rowbase[N_NODES_C] = N_EDGES_C;
    __syncthreads();
    for (int i = t; i < n; i += 256) {
        unsigned int v = csr[base + i];
        int tl = v >> 17;
        int pos = atomicAdd(&cur[tl], 1);
        csr2[pos] = (int)(v & 0x1FFFF);
    }
}

// ---------- hs = (x @ W^T) * dinv[row]  -> bf16 ----------
__global__ __launch_bounds__(256) void gemm_kernel(const float* __restrict__ x,
                                                   const float* __restrict__ W,
                                                   const float* __restrict__ dinv,
                                                   unsigned short* __restrict__ hs) {
    __shared__ float Wl[DIM * 65];
    __shared__ float xs[32][DIM];
    int t = threadIdx.x;
    for (int i = t; i < DIM * DIM; i += 256) {
        Wl[(i >> 6) * 65 + (i & 63)] = W[i];
    }
    int r0 = blockIdx.x * 32;
    for (int i = t; i < 32 * DIM; i += 256) {
        int row = i >> 6, col = i & 63;
        int r = r0 + row;
        xs[row][col] = (r < N_NODES_C) ? x[(size_t)r * DIM + col] : 0.0f;
    }
    __syncthreads();
    int wv = t >> 6, c = t & 63;
    for (int it = 0; it < 8; ++it) {
        int rl = it * 4 + wv;
        int r = r0 + rl;
        float acc = 0.0f;
#pragma unroll
        for (int k = 0; k < DIM; ++k) acc += xs[rl][k] * Wl[c * 65 + k];
        if (r < N_NODES_C) hs[(size_t)r * DIM + c] = f2bf(acc * dinv[r]);
    }
}

// ---------- gather: half-wave per node; row indices loaded with ONE coalesced
// vector load + in-register __shfl distribution -> hs gathers have no memory
// dependency and issue 8-16 deep (ping-pong A/B schedule, uniform branches).
// out[t] = (sum_src hs[src] + hs[t]) * dinv[t] + b ; fused BN stats ----------
__global__ __launch_bounds__(256) void gather_kernel(const int* __restrict__ csr2,
                                                     const int* __restrict__ rowbase,
                                                     const float* __restrict__ dinv,
                                                     const unsigned int* __restrict__ hs2,
                                                     const float* __restrict__ b_,
                                                     float2* __restrict__ out,
                                                     float* __restrict__ sums,
                                                     float* __restrict__ sumsq) {
    int lane = threadIdx.x & 63;
    int half = lane >> 5;
    int c2 = lane & 31;
    int wid = blockIdx.x * (blockDim.x >> 6) + (threadIdx.x >> 6);
    int nw = gridDim.x * (blockDim.x >> 6);
    float2 bb = ((const float2*)b_)[c2];
    float s0a = 0.0f, q0a = 0.0f, s1a = 0.0f, q1a = 0.0f;

#define ISSUE8(BUF, KB)                                                        \
    _Pragma("unroll")                                                          \
    for (int k = 0; k < 8; ++k) {                                              \
        int s = __shfl(idxv, (KB) + k, 32);                                    \
        BUF[k] = hs2[(size_t)s * 32 + c2];                                     \
    }
#define CONSUME8(BUF, KB)                                                      \
    _Pragma("unroll")                                                          \
    for (int k = 0; k < 8; ++k) {                                              \
        bool use = ((KB) + k) < nl;                                            \
        a0 += use ? bflo(BUF[k]) : 0.0f;                                       \
        a1 += use ? bfhi(BUF[k]) : 0.0f;                                       \
    }

    for (int p = wid; p < N_NODES_C / 2; p += nw) {
        int t = 2 * p + half;
        int base = rowbase[t];
        int end = rowbase[t + 1];
        int n = end - base;
        int n_oth = __shfl_xor(n, 32, 64);
        int nmax = max(n, n_oth);            // wave-uniform
        float a0 = 0.0f, a1 = 0.0f;
        for (int kd = 0; kd < nmax; kd += 32) {
            int nl = n - kd;                 // remaining edges this half (may be <=0)
            int off = (nl > 0) ? min(c2, nl - 1) : 0;
            int pos = min(base + kd + off, N_EDGES_C - 1);
            int idxv = csr2[pos];            // one coalesced load: 32 indices/half
            int nml = min(nmax - kd, 32);    // wave-uniform
            unsigned int uA[8], uB[8];
            ISSUE8(uA, 0);
            if (nml > 8)  { ISSUE8(uB, 8); }
            CONSUME8(uA, 0);
            if (nml > 16) { ISSUE8(uA, 16); }
            if (nml > 8)  { CONSUME8(uB, 8); }
            if (nml > 24) { ISSUE8(uB, 24); }
            if (nml > 16) { CONSUME8(uA, 16); }
            if (nml > 24) { CONSUME8(uB, 24); }
        }
        unsigned int ut = hs2[(size_t)t * 32 + c2];
        float dt = dinv[t];
        a0 = fmaf(a0 + bflo(ut), dt, bb.x);
        a1 = fmaf(a1 + bfhi(ut), dt, bb.y);
        out[(size_t)t * 32 + c2] = make_float2(a0, a1);
        s0a += a0; q0a += a0 * a0;
        s1a += a1; q1a += a1 * a1;
    }
#undef ISSUE8
#undef CONSUME8

    __shared__ float r0[256], r1[256], r2[256], r3[256];
    r0[threadIdx.x] = s0a; r1[threadIdx.x] = q0a;
    r2[threadIdx.x] = s1a; r3[threadIdx.x] = q1a;
    __syncthreads();
    if (threadIdx.x < 32) {
        float S0 = 0, Q0 = 0, S1 = 0, Q1 = 0;
        for (int k = threadIdx.x; k < 256; k += 32) {
            S0 += r0[k]; Q0 += r1[k]; S1 += r2[k]; Q1 += r3[k];
        }
        unsafeAtomicAdd(&sums[2 * threadIdx.x], S0);
        unsafeAtomicAdd(&sums[2 * threadIdx.x + 1], S1);
        unsafeAtomicAdd(&sumsq[2 * threadIdx.x], Q0);
        unsafeAtomicAdd(&sumsq[2 * threadIdx.x + 1], Q1);
    }
}

// ---------- BN params derived in-block + apply + ReLU ----------
__global__ __launch_bounds__(256) void bnrelu_kernel(float4* __restrict__ out,
                                                     const float* __restrict__ sums,
                                                     const float* __restrict__ sumsq,
                                                     const float* __restrict__ gamma,
                                                     const float* __restrict__ beta) {
    __shared__ float sc[DIM], sh[DIM];
    int t = threadIdx.x;
    if (t < DIM) {
        float m = sums[t] * (1.0f / N_NODES_C);
        float var = sumsq[t] * (1.0f / N_NODES_C) - m * m;
        float s = gamma[t] * rsqrtf(var + BN_EPS_C);
        sc[t] = s;
        sh[t] = beta[t] - m * s;
    }
    __syncthreads();
    const int n4 = N_NODES_C * (DIM / 4);
    int stride = gridDim.x * blockDim.x;
    for (int i = blockIdx.x * blockDim.x + t; i < n4; i += stride) {
        int cb = (i & 15) * 4;
        float4 v = out[i];
        v.x = fmaxf(fmaf(v.x, sc[cb + 0], sh[cb + 0]), 0.0f);
        v.y = fmaxf(fmaf(v.y, sc[cb + 1], sh[cb + 1]), 0.0f);
        v.z = fmaxf(fmaf(v.z, sc[cb + 2], sh[cb + 2]), 0.0f);
        v.w = fmaxf(fmaf(v.w, sc[cb + 3], sh[cb + 3]), 0.0f);
        out[i] = v;
    }
}

extern "C" void kernel_launch(void* const* d_in, const int* in_sizes, int n_in,
                              void* d_out, int out_size, void* d_ws, size_t ws_size,
                              hipStream_t stream) {
    const float* x     = (const float*)d_in[0];
    const void*  ei    = d_in[1];
    const float* W     = (const float*)d_in[2];
    const float* b     = (const float*)d_in[3];
    const float* gamma = (const float*)d_in[4];
    const float* beta  = (const float*)d_in[5];
    float* out = (float*)d_out;

    char* ws = (char*)d_ws;
    int*   bucket_cnt    = (int*)(ws + 256);      // 3328 B
    int*   bucket_base   = (int*)(ws + 3584);     // 3328 B
    int*   bucket_cursor = (int*)(ws + 6912);     // 3328 B
    float* dinv          = (float*)(ws + 10240);  // 400000 B
    int*   rowbase       = (int*)(ws + 410240);   // 400004 B (+pad)
    float* sums          = (float*)(ws + 810496); // 256 B
    float* sumsq         = (float*)(ws + 810752); // 256 B
    unsigned int* csr    = (unsigned int*)(ws + 811520);   // 6,400,000 B
    int*   csr2          = (int*)(ws + 7211520);           // 6,400,000 B
    unsigned short* hs   = (unsigned short*)(ws + 13611520); // 12,800,000 B

    hipMemsetAsync(bucket_cnt, 0, NB * sizeof(int), stream);
    hipMemsetAsync(sums, 0, 512, stream);  // sums + sumsq contiguous

    hist_kernel<<<256, 256, 0, stream>>>(ei, bucket_cnt);
    bucketscan_kernel<<<1, 1024, 0, stream>>>(bucket_cnt, bucket_base, bucket_cursor);
    binscatter_kernel<<<(N_EDGES_C + CH - 1) / CH, 256, 0, stream>>>(ei, bucket_cursor, csr);
    sort_kernel<<<NB, 256, 0, stream>>>(csr, bucket_base, bucket_cnt, csr2,
                                        rowbase, dinv);
    gemm_kernel<<<(N_NODES_C + 31) / 32, 256, 0, stream>>>(x, W, dinv, hs);
    gather_kernel<<<2048, 256, 0, stream>>>(csr2, rowbase, dinv,
                                            (const unsigned int*)hs, b,
                                            (float2*)out, sums, sumsq);
    bnrelu_kernel<<<1024, 256, 0, stream>>>((float4*)out, sums, sumsq, gamma, beta);
}